// Round 1
// baseline (461.876 us; speedup 1.0000x reference)
//
#include <hip/hip_runtime.h>
#include <math.h>

#define S_ 2048
#define NH 8
#define DH 64
#define RSTRIDE 264   // padded row stride for R (r in [0,256] meaningful)

// ---------------------------------------------------------------------------
// Kernel 1: fused QKV GEMM.  x[4096,512] @ {Wq,Wk,Wv}[512,512] (fp32 vector).
// 128x128 tile, BK=16, 8x8 micro-tile per thread, 256 threads.
// widx==0 writes qcon(+b_con) AND qrel(+b_rel); widx==1 -> k; widx==2 -> v(+bv).
// ---------------------------------------------------------------------------
__global__ __launch_bounds__(256) void qkv_gemm(
    const float* __restrict__ x,
    const float* __restrict__ Wq, const float* __restrict__ Wk, const float* __restrict__ Wv,
    const float* __restrict__ b_con, const float* __restrict__ b_rel, const float* __restrict__ bv,
    float* __restrict__ qcon, float* __restrict__ qrel,
    float* __restrict__ kout, float* __restrict__ vout)
{
    __shared__ float As[16][136];   // [k][m], padded
    __shared__ float Bs[16][128];   // [k][n]
    const int tid = threadIdx.x;
    const int tx = tid & 15, ty = tid >> 4;
    const int m0 = blockIdx.x * 128;
    const int gn0 = blockIdx.y * 128;
    const int widx = gn0 >> 9;
    const int col0 = gn0 & 511;
    const float* W = (widx == 0) ? Wq : (widx == 1) ? Wk : Wv;

    float acc[8][8] = {};

    const int arow = tid >> 1, akof = (tid & 1) * 8;
    const int brow = tid >> 4, bcof = (tid & 15) * 8;

    for (int k0 = 0; k0 < 512; k0 += 16) {
        float4 a0 = *(const float4*)&x[(size_t)(m0 + arow) * 512 + k0 + akof];
        float4 a1 = *(const float4*)&x[(size_t)(m0 + arow) * 512 + k0 + akof + 4];
        float4 b0 = *(const float4*)&W[(size_t)(k0 + brow) * 512 + col0 + bcof];
        float4 b1 = *(const float4*)&W[(size_t)(k0 + brow) * 512 + col0 + bcof + 4];
        As[akof + 0][arow] = a0.x; As[akof + 1][arow] = a0.y;
        As[akof + 2][arow] = a0.z; As[akof + 3][arow] = a0.w;
        As[akof + 4][arow] = a1.x; As[akof + 5][arow] = a1.y;
        As[akof + 6][arow] = a1.z; As[akof + 7][arow] = a1.w;
        *(float4*)&Bs[brow][bcof] = b0;
        *(float4*)&Bs[brow][bcof + 4] = b1;
        __syncthreads();
#pragma unroll
        for (int kk = 0; kk < 16; ++kk) {
            float a[8], bb[8];
            *(float4*)&a[0] = *(const float4*)&As[kk][ty * 8];
            *(float4*)&a[4] = *(const float4*)&As[kk][ty * 8 + 4];
            *(float4*)&bb[0] = *(const float4*)&Bs[kk][tx * 8];
            *(float4*)&bb[4] = *(const float4*)&Bs[kk][tx * 8 + 4];
#pragma unroll
            for (int i = 0; i < 8; ++i)
#pragma unroll
                for (int j = 0; j < 8; ++j) acc[i][j] += a[i] * bb[j];
        }
        __syncthreads();
    }

    const int col = col0 + tx * 8;
    if (widx == 0) {
        float bc[8], br[8];
        *(float4*)&bc[0] = *(const float4*)&b_con[col];
        *(float4*)&bc[4] = *(const float4*)&b_con[col + 4];
        *(float4*)&br[0] = *(const float4*)&b_rel[col];
        *(float4*)&br[4] = *(const float4*)&b_rel[col + 4];
#pragma unroll
        for (int i = 0; i < 8; ++i) {
            size_t base = (size_t)(m0 + ty * 8 + i) * 512 + col;
            float o1[8], o2[8];
#pragma unroll
            for (int j = 0; j < 8; ++j) { o1[j] = acc[i][j] + bc[j]; o2[j] = acc[i][j] + br[j]; }
            *(float4*)&qcon[base]     = *(float4*)&o1[0];
            *(float4*)&qcon[base + 4] = *(float4*)&o1[4];
            *(float4*)&qrel[base]     = *(float4*)&o2[0];
            *(float4*)&qrel[base + 4] = *(float4*)&o2[4];
        }
    } else if (widx == 1) {
#pragma unroll
        for (int i = 0; i < 8; ++i) {
            size_t base = (size_t)(m0 + ty * 8 + i) * 512 + col;
            *(float4*)&kout[base]     = *(float4*)&acc[i][0];
            *(float4*)&kout[base + 4] = *(float4*)&acc[i][4];
        }
    } else {
        float bb[8];
        *(float4*)&bb[0] = *(const float4*)&bv[col];
        *(float4*)&bb[4] = *(const float4*)&bv[col + 4];
#pragma unroll
        for (int i = 0; i < 8; ++i) {
            size_t base = (size_t)(m0 + ty * 8 + i) * 512 + col;
            float o[8];
#pragma unroll
            for (int j = 0; j < 8; ++j) o[j] = acc[i][j] + bb[j];
            *(float4*)&vout[base]     = *(float4*)&o[0];
            *(float4*)&vout[base + 4] = *(float4*)&o[4];
        }
    }
}

// ---------------------------------------------------------------------------
// Kernel 2: krel[r,e] = pos_emb_row(r) @ Wkr, r in [0,256] (only rel positions
// the band can touch).  pos row r: elem 2f = sin(r*invf(f)), 2f+1 = cos(...).
// 64x64 tile, A generated on the fly.
// ---------------------------------------------------------------------------
__global__ __launch_bounds__(256) void krel_gemm(
    const float* __restrict__ Wkr, float* __restrict__ krel)
{
    __shared__ float As[16][68];
    __shared__ float Bs[16][64];
    const int tid = threadIdx.x;
    const int tx = tid & 15, ty = tid >> 4;
    const int m0 = blockIdx.x * 64;
    const int col0 = blockIdx.y * 64;
    float acc[4][4] = {};
    const int arow = tid >> 2, ak4 = (tid & 3) * 4;
    const int brow = tid >> 4, bc4 = (tid & 15) * 4;
    const float rpos = (float)(m0 + arow);
    const float C = -0.051905126482615036f;   // -log2(10000)/256

    for (int k0 = 0; k0 < 512; k0 += 16) {
#pragma unroll
        for (int c = 0; c < 4; ++c) {
            int kg = k0 + ak4 + c;
            int f = kg >> 1;
            float invf = exp2f(C * (float)f);
            float ang = rpos * invf;
            As[ak4 + c][arow] = (kg & 1) ? cosf(ang) : sinf(ang);
        }
        *(float4*)&Bs[brow][bc4] =
            *(const float4*)&Wkr[(size_t)(k0 + brow) * 512 + col0 + bc4];
        __syncthreads();
#pragma unroll
        for (int kk = 0; kk < 16; ++kk) {
            float a[4], bb[4];
            *(float4*)&a[0]  = *(const float4*)&As[kk][ty * 4];
            *(float4*)&bb[0] = *(const float4*)&Bs[kk][tx * 4];
#pragma unroll
            for (int i = 0; i < 4; ++i)
#pragma unroll
                for (int j = 0; j < 4; ++j) acc[i][j] += a[i] * bb[j];
        }
        __syncthreads();
    }
#pragma unroll
    for (int i = 0; i < 4; ++i) {
        int r = m0 + ty * 4 + i;
        if (r <= 256) {
            float4 o = {acc[i][0], acc[i][1], acc[i][2], acc[i][3]};
            *(float4*)&krel[(size_t)r * 512 + col0 + tx * 4] = o;
        }
    }
}

// ---------------------------------------------------------------------------
// Kernel 3: R[b,n,i,r] = qrel[b,i,n,:] . krel[r,n,:]   (r in [0,256])
// One block per (b,n, 64-i tile); 5 chunks of 64 r.  Register-blocked 4 rows.
// ---------------------------------------------------------------------------
__global__ __launch_bounds__(256) void rel_gemm(
    const float* __restrict__ qrel, const float* __restrict__ krel,
    float* __restrict__ R)
{
    const int tile = blockIdx.x, n = blockIdx.y, b = blockIdx.z;
    const int i0 = tile * 64;
    const int tid = threadIdx.x, lane = tid & 63, w = tid >> 6;
    __shared__ float q_lds[64][64];    // broadcast reads -> no pad needed
    __shared__ float kr_lds[64][68];   // lane-indexed float4 reads -> stride 68
    const int srow = tid >> 2, sc0 = (tid & 3) * 4;
#pragma unroll
    for (int c = 0; c < 4; ++c) {
        int d = sc0 + c * 16;
        *(float4*)&q_lds[srow][d] =
            *(const float4*)&qrel[((size_t)b * S_ + i0 + srow) * 512 + n * 64 + d];
    }
    const size_t rbase = ((size_t)(b * NH + n) * S_ + i0) * RSTRIDE;
    for (int rc = 0; rc < 5; ++rc) {
#pragma unroll
        for (int c = 0; c < 4; ++c) {
            int d = sc0 + c * 16;
            int rr = rc * 64 + srow;
            float4 kv = make_float4(0.f, 0.f, 0.f, 0.f);
            if (rr <= 256) kv = *(const float4*)&krel[(size_t)rr * 512 + n * 64 + d];
            *(float4*)&kr_lds[srow][d] = kv;
        }
        __syncthreads();
#pragma unroll 1
        for (int pg = 0; pg < 4; ++pg) {
            float dot[4] = {0.f, 0.f, 0.f, 0.f};
#pragma unroll
            for (int d4 = 0; d4 < 16; ++d4) {
                float4 k4 = *(const float4*)&kr_lds[lane][d4 * 4];
#pragma unroll
                for (int rr2 = 0; rr2 < 4; ++rr2) {
                    float4 q4 = *(const float4*)&q_lds[w * 16 + pg * 4 + rr2][d4 * 4];
                    dot[rr2] += q4.x * k4.x + q4.y * k4.y + q4.z * k4.z + q4.w * k4.w;
                }
            }
            int rg = rc * 64 + lane;
            if (rg < RSTRIDE) {
#pragma unroll
                for (int rr2 = 0; rr2 < 4; ++rr2)
                    R[rbase + (size_t)(w * 16 + pg * 4 + rr2) * RSTRIDE + rg] = dot[rr2];
            }
        }
        __syncthreads();
    }
}

// ---------------------------------------------------------------------------
// Kernel 4: vmean[b,e] = (1/S) sum_s v[b,s,e]   (fallback for fully-masked rows:
// reference's energy-1e30 collapses to uniform softmax over ALL keys)
// ---------------------------------------------------------------------------
__global__ __launch_bounds__(512) void vmean_kernel(
    const float* __restrict__ v, float* __restrict__ vmean)
{
    const int b = blockIdx.x, sc = blockIdx.y;
    const int e = threadIdx.x;
    float sum = 0.f;
    for (int s = sc * 64; s < sc * 64 + 64; ++s)
        sum += v[((size_t)b * S_ + s) * 512 + e];
    atomicAdd(&vmean[(size_t)b * 512 + e], sum * (1.0f / (float)S_));
}

// ---------------------------------------------------------------------------
// Kernel 5: banded flash attention.
// Block = (b, n, 64-query tile), 256 threads (4 waves x 16 rows each).
// 5 key-chunks of 64; online softmax with -1e30 sentinel (garbage chunks
// self-wipe via alpha = exp(-1e30) = 0).  k_lds is re-used to hold p after a
// barrier, keeping static LDS at 50 KB (3 blocks/CU).
// ---------------------------------------------------------------------------
__global__ __launch_bounds__(256) void attn_kernel(
    const float* __restrict__ qcon, const float* __restrict__ kbuf,
    const float* __restrict__ vbuf, const float* __restrict__ R,
    const float* __restrict__ vmean, const int* __restrict__ xlen_p,
    float* __restrict__ out)
{
    const int tile = blockIdx.x, n = blockIdx.y, b = blockIdx.z;
    const int i0 = tile * 64;
    const int tid = threadIdx.x, lane = tid & 63, w = tid >> 6;
    const int xlen = xlen_p[b];

    __shared__ float q_lds[64][64];    // broadcast-only reads
    __shared__ float k_lds[64][68];    // [j][d]; later aliased to hold p[i][j]
    __shared__ float vT_lds[64][68];   // [d][j]

    const int srow = tid >> 2, sc0 = (tid & 3) * 4;
#pragma unroll
    for (int c = 0; c < 4; ++c) {
        int d = sc0 + c * 16;
        *(float4*)&q_lds[srow][d] =
            *(const float4*)&qcon[((size_t)b * S_ + i0 + srow) * 512 + n * 64 + d];
    }

    float acc[16], m_p[16], l_p[16], pv[16];
#pragma unroll
    for (int p = 0; p < 16; ++p) { acc[p] = 0.f; m_p[p] = -1e30f; l_p[p] = 0.f; }

    const size_t rrow0 = ((size_t)(b * NH + n) * S_ + i0) * RSTRIDE;

#pragma unroll 1
    for (int c = 0; c < 5; ++c) {
        const int jc0 = i0 - 256 + c * 64;
        // ---- stage k chunk and transposed v chunk ----
#pragma unroll
        for (int cc = 0; cc < 4; ++cc) {
            int d = sc0 + cc * 16;
            int jgs = jc0 + srow;
            float4 kv = make_float4(0.f, 0.f, 0.f, 0.f);
            float4 vv = make_float4(0.f, 0.f, 0.f, 0.f);
            if (jgs >= 0) {
                kv = *(const float4*)&kbuf[((size_t)b * S_ + jgs) * 512 + n * 64 + d];
                vv = *(const float4*)&vbuf[((size_t)b * S_ + jgs) * 512 + n * 64 + d];
            }
            *(float4*)&k_lds[srow][d] = kv;
            vT_lds[d + 0][srow] = vv.x; vT_lds[d + 1][srow] = vv.y;
            vT_lds[d + 2][srow] = vv.z; vT_lds[d + 3][srow] = vv.w;
        }
        __syncthreads();

        const int jg = jc0 + lane;
        // ---- scores + online softmax update (p in registers) ----
#pragma unroll
        for (int pg = 0; pg < 4; ++pg) {
            float dot[4] = {0.f, 0.f, 0.f, 0.f};
#pragma unroll
            for (int d4 = 0; d4 < 16; ++d4) {
                float4 k4 = *(const float4*)&k_lds[lane][d4 * 4];
#pragma unroll
                for (int rr = 0; rr < 4; ++rr) {
                    float4 q4 = *(const float4*)&q_lds[w * 16 + pg * 4 + rr][d4 * 4];
                    dot[rr] += q4.x * k4.x + q4.y * k4.y + q4.z * k4.z + q4.w * k4.w;
                }
            }
#pragma unroll
            for (int rr = 0; rr < 4; ++rr) {
                const int p = pg * 4 + rr;
                const int i = i0 + w * 16 + p;
                const int r = i - jg;
                const bool valid = (jg >= 0) && (r >= 0) && (r <= 256) && (jg < xlen);
                float rv = valid ? R[rrow0 + (size_t)(w * 16 + p) * RSTRIDE + r] : 0.f;
                float s = valid ? (dot[rr] + rv) * 0.125f : -1e30f;
                float mx = s;
#pragma unroll
                for (int off = 32; off >= 1; off >>= 1)
                    mx = fmaxf(mx, __shfl_xor(mx, off, 64));
                float mnew = fmaxf(m_p[p], mx);
                float alpha = __expf(m_p[p] - mnew);
                float e = __expf(s - mnew);
                float sum = e;
#pragma unroll
                for (int off = 32; off >= 1; off >>= 1)
                    sum += __shfl_xor(sum, off, 64);
                l_p[p] = l_p[p] * alpha + sum;
                m_p[p] = mnew;
                acc[p] *= alpha;
                pv[p] = e;
            }
        }
        __syncthreads();   // all waves done reading k_lds -> safe to overwrite with p
#pragma unroll
        for (int p = 0; p < 16; ++p) k_lds[w * 16 + p][lane] = pv[p];
        // ---- PV: acc[i][d=lane] += sum_j p[i][j] * v[j][d] ----
#pragma unroll
        for (int pg = 0; pg < 4; ++pg) {
            float a0 = acc[pg * 4 + 0], a1 = acc[pg * 4 + 1];
            float a2 = acc[pg * 4 + 2], a3 = acc[pg * 4 + 3];
#pragma unroll
            for (int j4 = 0; j4 < 16; ++j4) {
                float4 v4 = *(const float4*)&vT_lds[lane][j4 * 4];
                float4 p0 = *(const float4*)&k_lds[w * 16 + pg * 4 + 0][j4 * 4];
                float4 p1 = *(const float4*)&k_lds[w * 16 + pg * 4 + 1][j4 * 4];
                float4 p2 = *(const float4*)&k_lds[w * 16 + pg * 4 + 2][j4 * 4];
                float4 p3 = *(const float4*)&k_lds[w * 16 + pg * 4 + 3][j4 * 4];
                a0 += p0.x * v4.x + p0.y * v4.y + p0.z * v4.z + p0.w * v4.w;
                a1 += p1.x * v4.x + p1.y * v4.y + p1.z * v4.z + p1.w * v4.w;
                a2 += p2.x * v4.x + p2.y * v4.y + p2.z * v4.z + p2.w * v4.w;
                a3 += p3.x * v4.x + p3.y * v4.y + p3.z * v4.z + p3.w * v4.w;
            }
            acc[pg * 4 + 0] = a0; acc[pg * 4 + 1] = a1;
            acc[pg * 4 + 2] = a2; acc[pg * 4 + 3] = a3;
        }
        __syncthreads();   // protect k_lds(p)/vT_lds before next chunk staging
    }

    // ---- epilogue ----
#pragma unroll
    for (int p = 0; p < 16; ++p) {
        const int i = i0 + w * 16 + p;
        float val;
        if (i >= xlen + 256) val = vmean[(size_t)b * 512 + n * 64 + lane];
        else                 val = acc[p] / l_p[p];
        out[((size_t)b * S_ + i) * 512 + n * 64 + lane] = val;
    }
}

// ---------------------------------------------------------------------------
extern "C" void kernel_launch(void* const* d_in, const int* in_sizes, int n_in,
                              void* d_out, int out_size, void* d_ws, size_t ws_size,
                              hipStream_t stream) {
    const float* x     = (const float*)d_in[0];
    const float* Wq    = (const float*)d_in[1];
    const float* b_con = (const float*)d_in[2];
    const float* b_rel = (const float*)d_in[3];
    const float* Wk    = (const float*)d_in[4];
    const float* Wkr   = (const float*)d_in[5];
    const float* Wv    = (const float*)d_in[6];
    const float* bv    = (const float*)d_in[7];
    const int*   xlen  = (const int*)d_in[8];
    float* out = (float*)d_out;

    float* ws = (float*)d_ws;
    float* qcon  = ws;                     // 4096*512
    float* qrel  = qcon  + 2097152;        // 4096*512
    float* kbuf  = qrel  + 2097152;        // 4096*512
    float* vbuf  = kbuf  + 2097152;        // 4096*512
    float* krel  = vbuf  + 2097152;        // 257*512 (rounded region)
    float* vmean = krel  + 131584;         // 2*512
    float* R     = vmean + 1024;           // 2*8*2048*264

    hipMemsetAsync(vmean, 0, 1024 * sizeof(float), stream);

    qkv_gemm<<<dim3(32, 12), 256, 0, stream>>>(x, Wq, Wk, Wv, b_con, b_rel, bv,
                                               qcon, qrel, kbuf, vbuf);
    krel_gemm<<<dim3(5, 8), 256, 0, stream>>>(Wkr, krel);
    rel_gemm<<<dim3(32, 8, 2), 256, 0, stream>>>(qrel, krel, R);
    vmean_kernel<<<dim3(2, 32), 512, 0, stream>>>(vbuf, vmean);
    attn_kernel<<<dim3(32, 8, 2), 256, 0, stream>>>(qcon, kbuf, vbuf, R, vmean,
                                                    xlen, out);
}